// Round 3
// baseline (6758.364 us; speedup 1.0000x reference)
//
#include <hip/hip_runtime.h>

typedef _Float16 f16;
typedef _Float16 half8 __attribute__((ext_vector_type(8)));
typedef float f32x4 __attribute__((ext_vector_type(4)));
typedef unsigned int u32;
typedef u32 u32x4 __attribute__((ext_vector_type(4)));

__device__ inline float frcp(float x) {
#if __has_builtin(__builtin_amdgcn_rcpf)
  return __builtin_amdgcn_rcpf(x);
#else
  return 1.0f / x;
#endif
}
__device__ inline float fexp2(float x) {
#if __has_builtin(__builtin_amdgcn_exp2f)
  return __builtin_amdgcn_exp2f(x);
#else
  return exp2f(x);
#endif
}

// ---------------- small prep kernels ----------------

__global__ void k_cvt(const float* __restrict__ s, f16* __restrict__ d, int n) {
  int i = blockIdx.x * 256 + threadIdx.x;
  if (i < n) d[i] = (f16)s[i];
}

__global__ void k_zero(u32* __restrict__ p, int n) {
  int i = blockIdx.x * 256 + threadIdx.x;
  if (i < n) p[i] = 0u;
}

// w0 [1024][89] -> padded f16 [1024][96]
__global__ void k_w0pad(const float* __restrict__ w0, f16* __restrict__ d) {
  int i = blockIdx.x * 256 + threadIdx.x;
  if (i >= 1024 * 96) return;
  int row = i / 96, c = i % 96;
  d[i] = (c < 89) ? (f16)w0[row * 89 + c] : (f16)0.f;
}

// xb0 f16 [128][500][96]: s<64: x[s][t][f]; s>=64: x[s-64][499-t][f]; pad f>=89 with 0
__global__ void k_xb0(const float* __restrict__ x, f16* __restrict__ d) {
  int i = blockIdx.x * 256 + threadIdx.x;
  if (i >= 128 * 500 * 96) return;
  int f = i % 96;
  int t = (i / 96) % 500;
  int s = i / (96 * 500);
  float v = 0.f;
  if (f < 89) {
    if (s < 64) v = x[((size_t)s * 500 + t) * 89 + f];
    else        v = x[((size_t)(s - 64) * 500 + (499 - t)) * 89 + f];
  }
  d[i] = (f16)v;
}

__global__ void k_offs(const int* __restrict__ lens, int* __restrict__ offs) {
  if (threadIdx.x == 0 && blockIdx.x == 0) {
    int s = 0;
    for (int i = 0; i < 64; ++i) { offs[i] = s; s += lens[i]; }
  }
}

// ---------------- gates GEMM ----------------
// gates[t][s][n] = bias[n] + sum_k X(s,t,k) * W[n][k],  f16 out, layout [T][128][1024]
// LDS tiles: [128 rows][32 f16] as 4x 16B chunks/row, chunk ^= (row>>1)&3 (bank-
// conflict-free for both the 2-lane/row staging writes and the c-row fragment reads).
template <int MODE>
__global__ __launch_bounds__(256) void k_gates(const f16* __restrict__ Aw,
                                               const f16* __restrict__ W16,
                                               const float* __restrict__ bias,
                                               f16* __restrict__ gates) {
  constexpr int KW = MODE ? 1024 : 96;
  const int t = blockIdx.x;
  const int nb = blockIdx.y * 128;
  const int tid = threadIdx.x;
  const int w = tid >> 6, l = tid & 63, c = l & 15, rg = l >> 4;
  const int wr = w >> 1, wc = w & 1;

  __shared__ f16 As[128 * 32];
  __shared__ f16 Bs[128 * 32];

  f32x4 acc[4][4] = {};

  const int srow = tid >> 1;
  const int seg = (tid & 1) * 16;
  const int ch0 = seg >> 3;           // 0 or 2
  const int wsw = (srow >> 1) & 3;    // write-side chunk swizzle

  for (int kb = 0; kb < KW; kb += 32) {
    const f16* pa;
    if (MODE == 0) {
      pa = Aw + ((size_t)srow * 500 + t) * 96 + kb + seg;
    } else {
      int f0 = kb + seg;
      int half = f0 >> 9;
      int col = f0 & 511;
      int s = srow;
      int seq, time;
      if (s < 64) { seq = half ? 64 + s : s;  time = half ? 499 - t : t; }
      else        { seq = half ? s : s - 64;  time = half ? t : 499 - t; }
      pa = Aw + ((size_t)seq * 500 + time) * 512 + col;
    }
    const f16* pb = W16 + (size_t)(nb + srow) * KW + kb + seg;
    half8 a0 = *(const half8*)pa;
    half8 a1 = *(const half8*)(pa + 8);
    half8 b0 = *(const half8*)pb;
    half8 b1 = *(const half8*)(pb + 8);
    __syncthreads();
    *(half8*)&As[srow * 32 + ((ch0 + 0) ^ wsw) * 8] = a0;
    *(half8*)&As[srow * 32 + ((ch0 + 1) ^ wsw) * 8] = a1;
    *(half8*)&Bs[srow * 32 + ((ch0 + 0) ^ wsw) * 8] = b0;
    *(half8*)&Bs[srow * 32 + ((ch0 + 1) ^ wsw) * 8] = b1;
    __syncthreads();
    half8 aF[4], bF[4];
#pragma unroll
    for (int i = 0; i < 4; ++i) {
      int row = wr * 64 + i * 16 + c;
      aF[i] = *(const half8*)&As[row * 32 + ((rg ^ ((row >> 1) & 3)) * 8)];
    }
#pragma unroll
    for (int j = 0; j < 4; ++j) {
      int row = wc * 64 + j * 16 + c;
      bF[j] = *(const half8*)&Bs[row * 32 + ((rg ^ ((row >> 1) & 3)) * 8)];
    }
#pragma unroll
    for (int i = 0; i < 4; ++i)
#pragma unroll
      for (int j = 0; j < 4; ++j)
        acc[i][j] = __builtin_amdgcn_mfma_f32_16x16x32_f16(aF[i], bF[j], acc[i][j], 0, 0, 0);
  }

#pragma unroll
  for (int j = 0; j < 4; ++j) {
    int n = nb + wc * 64 + j * 16 + c;
    float bj = bias[n];
#pragma unroll
    for (int i = 0; i < 4; ++i) {
#pragma unroll
      for (int r = 0; r < 4; ++r) {
        int m = wr * 64 + i * 16 + rg * 4 + r;
        gates[((size_t)t * 128 + m) * 1024 + n] = (f16)(acc[i][j][r] + bj);
      }
    }
  }
}

// ---------------- recurrence (column-split, 64 WGs, tag-in-data sync) ----------------
// 64 WGs = 8 seq-groups (sg = blockIdx&7, 16 seqs) x 8 col-groups (cg, 64 cols).
// h exchanged as tagged u32 words (f16 payload | tag<<16), tag = tagbase + t, in
// agent-coherent hx[2][128][512]. Consumers poll the data words directly: the tag
// rides atomically with the value, so detection == data arrival (no counter RT).
// 2-buffer WAR safety: tag t+2 cannot be written to a buffer until every WG fully
// read tag t from it (full-tile reads precede each WG's t+1 tag stores, data-dep).
__global__ __launch_bounds__(256, 1) void k_rec(const f16* __restrict__ gates,
                                                const f16* __restrict__ U,    // [1024][512] f16
                                                f16* __restrict__ hs,         // [128][500][512] f16
                                                u32* __restrict__ hx,         // [2][128][512] u32
                                                int tagbase) {
  const int sg = blockIdx.x & 7, cg = blockIdx.x >> 3;
  const int tid = threadIdx.x;
  const int l = tid & 63, w = tid >> 6, c = l & 15, rg = l >> 4;
  const int s0 = sg * 16;
  const int hcol = cg * 64 + w * 16;
  const int an0 = hcol, zn0 = 512 + hcol;

  __shared__ f16 hlds[16 * 512];  // staged h tile, XOR-swizzled

  // U fragments: B[k][n] = U[n][k]; lane holds n = n0 + c, k = kt*32 + rg*8 + e
  half8 ua[16], uz[16];
#pragma unroll
  for (int kt = 0; kt < 16; ++kt) {
    ua[kt] = *(const half8*)(U + (size_t)(an0 + c) * 512 + kt * 32 + rg * 8);
    uz[kt] = *(const half8*)(U + (size_t)(zn0 + c) * 512 + kt * 32 + rg * 8);
  }
  // pin: make values opaque so the compiler keeps them register-resident
  // (r2: VGPR_Count=120 proved they were being re-loaded every step)
#pragma unroll
  for (int kt = 0; kt < 16; ++kt) {
    asm volatile("" : "+v"(ua[kt]));
    asm volatile("" : "+v"(uz[kt]));
  }

  float hold[4] = {0.f, 0.f, 0.f, 0.f};

  // preload gates t=0
  f16 ga[4], gz[4];
  {
    const f16* gb = gates + ((size_t)0 * 128 + s0 + rg * 4) * 1024;
#pragma unroll
    for (int r = 0; r < 4; ++r) { ga[r] = gb[r * 1024 + an0 + c]; gz[r] = gb[r * 1024 + zn0 + c]; }
  }

  for (int t = 0; t < 500; ++t) {
    // prefetch next step's gates (cached loads, fly during poll)
    int tn = (t + 1 < 500) ? t + 1 : 499;
    f16 gna[4], gnz[4];
    {
      const f16* gb = gates + ((size_t)tn * 128 + s0 + rg * 4) * 1024;
#pragma unroll
      for (int r = 0; r < 4; ++r) { gna[r] = gb[r * 1024 + an0 + c]; gnz[r] = gb[r * 1024 + zn0 + c]; }
    }

    // poll h^t (buf t&1): each thread owns 32 words = 8 vec4 slices
    u32x4 vv[8];
    if (t == 0) {
#pragma unroll
      for (int v = 0; v < 8; ++v) vv[v] = (u32x4){0u, 0u, 0u, 0u};
    } else {
      const u32 exp = (u32)(tagbase + t);
      const u32* hsrc = hx + (size_t)(t & 1) * 65536 + (size_t)s0 * 512 + tid * 4;
      unsigned mask = 0xffu;
      int guard = 0;
      while (mask) {
#pragma unroll
        for (int v = 0; v < 8; ++v) {
          if (mask & (1u << v)) {
            u32 a  = __hip_atomic_load(hsrc + v * 1024 + 0, __ATOMIC_RELAXED, __HIP_MEMORY_SCOPE_AGENT);
            u32 b  = __hip_atomic_load(hsrc + v * 1024 + 1, __ATOMIC_RELAXED, __HIP_MEMORY_SCOPE_AGENT);
            u32 cc = __hip_atomic_load(hsrc + v * 1024 + 2, __ATOMIC_RELAXED, __HIP_MEMORY_SCOPE_AGENT);
            u32 dd = __hip_atomic_load(hsrc + v * 1024 + 3, __ATOMIC_RELAXED, __HIP_MEMORY_SCOPE_AGENT);
            vv[v] = (u32x4){a, b, cc, dd};
          }
        }
#pragma unroll
        for (int v = 0; v < 8; ++v) {
          if (mask & (1u << v)) {
            if ((vv[v].x >> 16) == exp && (vv[v].y >> 16) == exp &&
                (vv[v].z >> 16) == exp && (vv[v].w >> 16) == exp)
              mask &= ~(1u << v);
          }
        }
        if (++guard > (1 << 14)) break;  // safety valve
      }
    }

    // stage payloads -> LDS (XOR swizzle on f16 idx bits 3..5)
#pragma unroll
    for (int v = 0; v < 8; ++v) {
      int elem = v * 1024 + tid * 4;
      int row = elem >> 9, col = elem & 511;
      u32 d0 = (vv[v].x & 0xffffu) | (vv[v].y << 16);
      u32 d1 = (vv[v].z & 0xffffu) | (vv[v].w << 16);
      int idx = (row * 512 + col) ^ ((row & 7) << 3);
      unsigned long long dd = (unsigned long long)d0 | ((unsigned long long)d1 << 32);
      *(unsigned long long*)&hlds[idx] = dd;
    }
    __syncthreads();

    // MFMA: acc = gates + h @ U^T  (A-frag: row=c, k=kt*32+rg*8+e)
    f32x4 acc_a, acc_z;
#pragma unroll
    for (int r = 0; r < 4; ++r) { acc_a[r] = (float)ga[r]; acc_z[r] = (float)gz[r]; }
#pragma unroll
    for (int kt = 0; kt < 16; ++kt) {
      int elem = (c * 512 + kt * 32 + rg * 8) ^ ((c & 7) << 3);
      half8 aF = *(const half8*)&hlds[elem];
      acc_a = __builtin_amdgcn_mfma_f32_16x16x32_f16(aF, ua[kt], acc_a, 0, 0, 0);
      acc_z = __builtin_amdgcn_mfma_f32_16x16x32_f16(aF, uz[kt], acc_z, 0, 0, 0);
    }

    // gating (lane-local; C layout: col=c, row=rg*4+r) + tagged stores first
    const u32 tagn = (u32)(tagbase + t + 1);
    u32* hdst = hx + (size_t)((t + 1) & 1) * 65536;
    float hnv[4];
#pragma unroll
    for (int r = 0; r < 4; ++r) {
      float av = acc_a[r];
      float zv = acc_z[r];
      float zs = frcp(1.f + fexp2(-1.44269504f * zv));   // sigmoid(z)
      float u2 = fexp2(2.88539008f * av);
      float th = 1.f - 2.f * frcp(u2 + 1.f);             // tanh(a)
      float hn = th + zs * (hold[r] - th);
      hold[r] = hn;
      hnv[r] = hn;
      u32 word = (u32)__builtin_bit_cast(unsigned short, (f16)hn) | (tagn << 16);
      __hip_atomic_store(&hdst[(size_t)(s0 + rg * 4 + r) * 512 + hcol + c], word,
                         __ATOMIC_RELAXED, __HIP_MEMORY_SCOPE_AGENT);
    }
    // hs output (off critical path)
#pragma unroll
    for (int r = 0; r < 4; ++r)
      hs[((size_t)(s0 + rg * 4 + r) * 500 + t) * 512 + hcol + c] = (f16)hnv[r];

#pragma unroll
    for (int r = 0; r < 4; ++r) { ga[r] = gna[r]; gz[r] = gnz[r]; }
  }
}

// ---------------- FC + pack ----------------
__global__ __launch_bounds__(256) void k_fc(const f16* __restrict__ hs,
                                            const f16* __restrict__ wfc,   // [72][1024] f16
                                            const float* __restrict__ bfc,
                                            const int* __restrict__ lens,
                                            const int* __restrict__ offs,
                                            float* __restrict__ out) {
  const int b = blockIdx.x, chunk = blockIdx.y;
  const int tid = threadIdx.x;
  __shared__ f16 X[16][1032];
#pragma unroll
  for (int ii = 0; ii < 8; ++ii) {
    int sg = ii * 256 + tid;
    int row = sg >> 7;
    int f = (sg & 127) * 8;
    int t = chunk * 16 + row;
    int tt = t < 500 ? t : 499;
    int half = f >> 9, col = f & 511;
    int seq = half ? 64 + b : b;
    int time = half ? 499 - tt : tt;
    *(half8*)&X[row][f] = *(const half8*)&hs[((size_t)seq * 500 + time) * 512 + col];
  }
  __syncthreads();
  int row = tid >> 4, og = tid & 15;
  int t = chunk * 16 + row;
  int len = lens[b];
  float acc[5];
#pragma unroll
  for (int j = 0; j < 5; ++j) {
    int o = j * 16 + og;
    acc[j] = (o < 72) ? bfc[o] : 0.f;
  }
  for (int k8 = 0; k8 < 128; ++k8) {
    half8 x8 = *(const half8*)&X[row][k8 * 8];
    float xf[8];
#pragma unroll
    for (int e = 0; e < 8; ++e) xf[e] = (float)x8[e];
#pragma unroll
    for (int j = 0; j < 5; ++j) {
      int o = j * 16 + og;
      int oc = o < 72 ? o : 0;
      half8 w8 = *(const half8*)&wfc[(size_t)oc * 1024 + k8 * 8];
#pragma unroll
      for (int e = 0; e < 8; ++e) acc[j] += xf[e] * (float)w8[e];
    }
  }
  if (t < 500 && t < len) {
    size_t base = ((size_t)offs[b] + t) * 72;
#pragma unroll
    for (int j = 0; j < 5; ++j) {
      int o = j * 16 + og;
      if (o < 72) out[base + o] = acc[j];
    }
  }
}

// ---------------- launcher ----------------

extern "C" void kernel_launch(void* const* d_in, const int* in_sizes, int n_in,
                              void* d_out, int out_size, void* d_ws, size_t ws_size,
                              hipStream_t stream) {
  const float* batch = (const float*)d_in[0];
  const int*   lens  = (const int*)d_in[1];
  const float* w0 = (const float*)d_in[2];
  const float* b0 = (const float*)d_in[3];
  const float* u0 = (const float*)d_in[4];
  const float* w1 = (const float*)d_in[5];
  const float* b1 = (const float*)d_in[6];
  const float* u1 = (const float*)d_in[7];
  const float* w2 = (const float*)d_in[8];
  const float* b2 = (const float*)d_in[9];
  const float* u2 = (const float*)d_in[10];
  const float* wfc = (const float*)d_in[11];
  const float* bfc = (const float*)d_in[12];
  float* out = (float*)d_out;

  char* ws = (char*)d_ws;
  const size_t GATES_OFF = 0;                  // [500][128][1024] f16 = 131,072,000
  const size_t HS_OFF    = 131072000;          // [128][500][512]  f16 =  65,536,000
  const size_t XB0_OFF   = 196608000;          // [128][500][96]   f16 =  12,288,000
  const size_t W0P_OFF   = 208896000;          // [1024][96]  f16
  const size_t W1_OFF    = 209092608;          // [1024][1024] f16
  const size_t W2_OFF    = 211189760;
  const size_t U0_OFF    = 213286912;          // [1024][512] f16
  const size_t U1_OFF    = 214335488;
  const size_t U2_OFF    = 215384064;
  const size_t WFC_OFF   = 216432640;          // [72][1024] f16
  const size_t OFFS_OFF  = 216580096;          // 64 ints
  const size_t HX_OFF    = 216581120;          // [2][128][512] u32 = 524,288 B

  f16* g_gates = (f16*)(ws + GATES_OFF);
  f16* g_hs    = (f16*)(ws + HS_OFF);
  f16* g_xb0   = (f16*)(ws + XB0_OFF);
  f16* g_w0p   = (f16*)(ws + W0P_OFF);
  f16* g_w1    = (f16*)(ws + W1_OFF);
  f16* g_w2    = (f16*)(ws + W2_OFF);
  f16* g_u0    = (f16*)(ws + U0_OFF);
  f16* g_u1    = (f16*)(ws + U1_OFF);
  f16* g_u2    = (f16*)(ws + U2_OFF);
  f16* g_wfc   = (f16*)(ws + WFC_OFF);
  int* g_offs  = (int*)(ws + OFFS_OFF);
  u32* g_hx    = (u32*)(ws + HX_OFF);

  hipLaunchKernelGGL(k_offs, dim3(1), dim3(64), 0, stream, lens, g_offs);

  auto cvt = [&](const float* s, f16* d, int n) {
    hipLaunchKernelGGL(k_cvt, dim3((n + 255) / 256), dim3(256), 0, stream, s, d, n);
  };
  cvt(w1, g_w1, 1024 * 1024);
  cvt(w2, g_w2, 1024 * 1024);
  cvt(u0, g_u0, 1024 * 512);
  cvt(u1, g_u1, 1024 * 512);
  cvt(u2, g_u2, 1024 * 512);
  cvt(wfc, g_wfc, 72 * 1024);
  hipLaunchKernelGGL(k_w0pad, dim3((1024 * 96 + 255) / 256), dim3(256), 0, stream, w0, g_w0p);
  hipLaunchKernelGGL(k_xb0, dim3((128 * 500 * 96 + 255) / 256), dim3(256), 0, stream, batch, g_xb0);
  // zero hx tags once; layer-encoded tags (l*512+t) make cross-layer staleness impossible
  hipLaunchKernelGGL(k_zero, dim3(512), dim3(256), 0, stream, g_hx, 131072);

  // layer 0
  hipLaunchKernelGGL((k_gates<0>), dim3(500, 8), dim3(256), 0, stream, g_xb0, g_w0p, b0, g_gates);
  hipLaunchKernelGGL(k_rec, dim3(64), dim3(256), 0, stream, g_gates, g_u0, g_hs, g_hx, 0);
  // layer 1
  hipLaunchKernelGGL((k_gates<1>), dim3(500, 8), dim3(256), 0, stream, g_hs, g_w1, b1, g_gates);
  hipLaunchKernelGGL(k_rec, dim3(64), dim3(256), 0, stream, g_gates, g_u1, g_hs, g_hx, 512);
  // layer 2
  hipLaunchKernelGGL((k_gates<1>), dim3(500, 8), dim3(256), 0, stream, g_hs, g_w2, b2, g_gates);
  hipLaunchKernelGGL(k_rec, dim3(64), dim3(256), 0, stream, g_gates, g_u2, g_hs, g_hx, 1024);

  // FC + pack
  hipLaunchKernelGGL(k_fc, dim3(64, 32), dim3(256), 0, stream, g_hs, g_wfc, bfc, lens, g_offs, out);
}

// Round 4
// 4897.593 us; speedup vs baseline: 1.3799x; 1.3799x over previous
//
#include <hip/hip_runtime.h>

typedef _Float16 f16;
typedef _Float16 half8 __attribute__((ext_vector_type(8)));
typedef float f32x4 __attribute__((ext_vector_type(4)));
typedef unsigned int u32;
typedef u32 u32x2 __attribute__((ext_vector_type(2)));
typedef u32 u32x4 __attribute__((ext_vector_type(4)));

__device__ inline float frcp(float x) {
#if __has_builtin(__builtin_amdgcn_rcpf)
  return __builtin_amdgcn_rcpf(x);
#else
  return 1.0f / x;
#endif
}
__device__ inline float fexp2(float x) {
#if __has_builtin(__builtin_amdgcn_exp2f)
  return __builtin_amdgcn_exp2f(x);
#else
  return exp2f(x);
#endif
}

// ---------------- small prep kernels ----------------

__global__ void k_cvt(const float* __restrict__ s, f16* __restrict__ d, int n) {
  int i = blockIdx.x * 256 + threadIdx.x;
  if (i < n) d[i] = (f16)s[i];
}

__global__ void k_zero(u32* __restrict__ p, int n) {
  int i = blockIdx.x * 256 + threadIdx.x;
  if (i < n) p[i] = 0u;
}

// w0 [1024][89] -> padded f16 [1024][96]
__global__ void k_w0pad(const float* __restrict__ w0, f16* __restrict__ d) {
  int i = blockIdx.x * 256 + threadIdx.x;
  if (i >= 1024 * 96) return;
  int row = i / 96, c = i % 96;
  d[i] = (c < 89) ? (f16)w0[row * 89 + c] : (f16)0.f;
}

// xb0 f16 [128][500][96]: s<64: x[s][t][f]; s>=64: x[s-64][499-t][f]; pad f>=89 with 0
__global__ void k_xb0(const float* __restrict__ x, f16* __restrict__ d) {
  int i = blockIdx.x * 256 + threadIdx.x;
  if (i >= 128 * 500 * 96) return;
  int f = i % 96;
  int t = (i / 96) % 500;
  int s = i / (96 * 500);
  float v = 0.f;
  if (f < 89) {
    if (s < 64) v = x[((size_t)s * 500 + t) * 89 + f];
    else        v = x[((size_t)(s - 64) * 500 + (499 - t)) * 89 + f];
  }
  d[i] = (f16)v;
}

__global__ void k_offs(const int* __restrict__ lens, int* __restrict__ offs) {
  if (threadIdx.x == 0 && blockIdx.x == 0) {
    int s = 0;
    for (int i = 0; i < 64; ++i) { offs[i] = s; s += lens[i]; }
  }
}

// ---------------- gates GEMM ----------------
// gates[t][s][n] = bias[n] + sum_k X(s,t,k) * W[n][k],  f16 out, layout [T][128][1024]
template <int MODE>
__global__ __launch_bounds__(256) void k_gates(const f16* __restrict__ Aw,
                                               const f16* __restrict__ W16,
                                               const float* __restrict__ bias,
                                               f16* __restrict__ gates) {
  constexpr int KW = MODE ? 1024 : 96;
  const int t = blockIdx.x;
  const int nb = blockIdx.y * 128;
  const int tid = threadIdx.x;
  const int w = tid >> 6, l = tid & 63, c = l & 15, rg = l >> 4;
  const int wr = w >> 1, wc = w & 1;

  __shared__ f16 As[128 * 32];
  __shared__ f16 Bs[128 * 32];

  f32x4 acc[4][4] = {};

  const int srow = tid >> 1;
  const int seg = (tid & 1) * 16;
  const int ch0 = seg >> 3;           // 0 or 2
  const int wsw = (srow >> 1) & 3;    // write-side chunk swizzle

  for (int kb = 0; kb < KW; kb += 32) {
    const f16* pa;
    if (MODE == 0) {
      pa = Aw + ((size_t)srow * 500 + t) * 96 + kb + seg;
    } else {
      int f0 = kb + seg;
      int half = f0 >> 9;
      int col = f0 & 511;
      int s = srow;
      int seq, time;
      if (s < 64) { seq = half ? 64 + s : s;  time = half ? 499 - t : t; }
      else        { seq = half ? s : s - 64;  time = half ? t : 499 - t; }
      pa = Aw + ((size_t)seq * 500 + time) * 512 + col;
    }
    const f16* pb = W16 + (size_t)(nb + srow) * KW + kb + seg;
    half8 a0 = *(const half8*)pa;
    half8 a1 = *(const half8*)(pa + 8);
    half8 b0 = *(const half8*)pb;
    half8 b1 = *(const half8*)(pb + 8);
    __syncthreads();
    *(half8*)&As[srow * 32 + ((ch0 + 0) ^ wsw) * 8] = a0;
    *(half8*)&As[srow * 32 + ((ch0 + 1) ^ wsw) * 8] = a1;
    *(half8*)&Bs[srow * 32 + ((ch0 + 0) ^ wsw) * 8] = b0;
    *(half8*)&Bs[srow * 32 + ((ch0 + 1) ^ wsw) * 8] = b1;
    __syncthreads();
    half8 aF[4], bF[4];
#pragma unroll
    for (int i = 0; i < 4; ++i) {
      int row = wr * 64 + i * 16 + c;
      aF[i] = *(const half8*)&As[row * 32 + ((rg ^ ((row >> 1) & 3)) * 8)];
    }
#pragma unroll
    for (int j = 0; j < 4; ++j) {
      int row = wc * 64 + j * 16 + c;
      bF[j] = *(const half8*)&Bs[row * 32 + ((rg ^ ((row >> 1) & 3)) * 8)];
    }
#pragma unroll
    for (int i = 0; i < 4; ++i)
#pragma unroll
      for (int j = 0; j < 4; ++j)
        acc[i][j] = __builtin_amdgcn_mfma_f32_16x16x32_f16(aF[i], bF[j], acc[i][j], 0, 0, 0);
  }

#pragma unroll
  for (int j = 0; j < 4; ++j) {
    int n = nb + wc * 64 + j * 16 + c;
    float bj = bias[n];
#pragma unroll
    for (int i = 0; i < 4; ++i) {
#pragma unroll
      for (int r = 0; r < 4; ++r) {
        int m = wr * 64 + i * 16 + rg * 4 + r;
        gates[((size_t)t * 128 + m) * 1024 + n] = (f16)(acc[i][j][r] + bj);
      }
    }
  }
}

// ---------------- recurrence (column-split, 64 WGs, flag-line protocol) ----------------
// 64 WGs = 8 seq-groups (sg = blockIdx&7, 16 seqs) x 8 col-groups (cg, 64 cols).
// h exchanged in MFMA-A-FRAGMENT-MAJOR f16 layout hx[2][8 sg][8192]: idx = kt*512+l*8+e
// holds h[row=l&15][col = kt*32+(l>>4)*8+e]. Producers shuffle their C-frag values
// through a 512B/wave LDS scratch so each lane emits ONE dwordx2 sc0sc1 store;
// consumers load the tile with 4x dwordx4 sc0sc1 and stage LDS *linearly* ->
// conflict-free b128 on both LDS sides. Sync: per-wave flag dwords (one 128B line
// per sg, no RMW contention), value = tagbase + t + 1 (monotone across layers).
__global__ __launch_bounds__(256, 1) void k_rec(const f16* __restrict__ gates,
                                                const f16* __restrict__ U,    // [1024][512] f16
                                                f16* __restrict__ hs,         // [128][500][512] f16
                                                f16* __restrict__ hx,         // [2][8][8192] f16
                                                u32* __restrict__ flags,      // [8][32]
                                                int tagbase) {
  const int sg = blockIdx.x & 7, cg = blockIdx.x >> 3;
  const int tid = threadIdx.x;
  const int l = tid & 63, w = tid >> 6, c = l & 15, rg = l >> 4;
  const int s0 = sg * 16;
  const int hcol = cg * 64 + w * 16;
  const int an0 = hcol, zn0 = 512 + hcol;

  __shared__ f16 hlds[8192 + 4 * 256];  // frag-major tile + per-wave shuffle scratch

  // U fragments: B[k][n] = U[n][k]; lane holds n = n0 + c, k = kt*32 + rg*8 + e
  half8 ua[16], uz[16];
#pragma unroll
  for (int kt = 0; kt < 16; ++kt) {
    ua[kt] = *(const half8*)(U + (size_t)(an0 + c) * 512 + kt * 32 + rg * 8);
    uz[kt] = *(const half8*)(U + (size_t)(zn0 + c) * 512 + kt * 32 + rg * 8);
  }

  float hold[4] = {0.f, 0.f, 0.f, 0.f};

  // gate preload for t=0
  f16 ga[4], gz[4];
  {
    const f16* gb = gates + ((size_t)0 * 128 + s0 + rg * 4) * 1024;
#pragma unroll
    for (int r = 0; r < 4; ++r) { ga[r] = gb[r * 1024 + an0 + c]; gz[r] = gb[r * 1024 + zn0 + c]; }
  }

  // producer-side constants
  const int ktp = cg * 2 + (w >> 1);
  const int pbase = ktp * 512 + (w & 1) * 256;        // wave's 256-f16 block in tile
  f16* scr = &hlds[8192 + w * 256];
  const int scri = (c >> 3) * 128 + (c & 7);          // + s*8 per r
  // hs-store coords for the shuffled lane data (4 consecutive cols, one row)
  const int srow2 = (l >> 1) & 15;
  const int col2 = ktp * 32 + ((w & 1) * 2 + (l >> 5)) * 8 + (l & 1) * 4;

  const size_t tileoff = (size_t)sg * 8192;

  for (int t = 0; t < 500; ++t) {
    // force U fragments register-resident THROUGH the loop (r3: one-time pin failed)
#pragma unroll
    for (int kt = 0; kt < 16; ++kt) asm volatile("" : "+v"(ua[kt]), "+v"(uz[kt]));

    u32x4 d0, d1, d2, d3;
    if (t == 0) {
      d0 = (u32x4){0u, 0u, 0u, 0u}; d1 = d0; d2 = d0; d3 = d0;
    } else {
      // poll per-wave flags: 1 dword/lane, one 128B line per sg
      const u32 tgt = (u32)(tagbase + t);
      const u32* fl = flags + sg * 32 + (l & 31);
      int guard = 0;
      for (;;) {
        u32 f = __hip_atomic_load(fl, __ATOMIC_RELAXED, __HIP_MEMORY_SCOPE_AGENT);
        if (__all((int)(f >= tgt))) break;
        if (++guard > (1 << 15)) break;  // safety valve
      }
      const f16* src = hx + (size_t)(t & 1) * 65536 + tileoff + (size_t)tid * 32;
      asm volatile("global_load_dwordx4 %0, %1, off sc0 sc1" : "=v"(d0) : "v"(src) : "memory");
      asm volatile("global_load_dwordx4 %0, %1, off sc0 sc1" : "=v"(d1) : "v"(src + 8) : "memory");
      asm volatile("global_load_dwordx4 %0, %1, off sc0 sc1" : "=v"(d2) : "v"(src + 16) : "memory");
      asm volatile("global_load_dwordx4 %0, %1, off sc0 sc1" : "=v"(d3) : "v"(src + 24) : "memory");
      asm volatile("s_waitcnt vmcnt(0)"
                   : "+v"(d0), "+v"(d1), "+v"(d2), "+v"(d3) : : "memory");
    }
    // linear LDS stage (conflict-free b128 writes)
    *(u32x4*)&hlds[tid * 32 + 0]  = d0;
    *(u32x4*)&hlds[tid * 32 + 8]  = d1;
    *(u32x4*)&hlds[tid * 32 + 16] = d2;
    *(u32x4*)&hlds[tid * 32 + 24] = d3;
    __syncthreads();

    // MFMA: acc = gates + h @ U^T ; A-frag read is the canonical consecutive-b128
    f32x4 acc_a, acc_z;
#pragma unroll
    for (int r = 0; r < 4; ++r) { acc_a[r] = (float)ga[r]; acc_z[r] = (float)gz[r]; }
#pragma unroll
    for (int kt = 0; kt < 16; ++kt) {
      half8 aF = *(const half8*)&hlds[kt * 512 + l * 8];
      acc_a = __builtin_amdgcn_mfma_f32_16x16x32_f16(aF, ua[kt], acc_a, 0, 0, 0);
      acc_z = __builtin_amdgcn_mfma_f32_16x16x32_f16(aF, uz[kt], acc_z, 0, 0, 0);
    }

    // gating (lane-local; C layout col=c, row=rg*4+r) -> frag-order shuffle via scratch
#pragma unroll
    for (int r = 0; r < 4; ++r) {
      float av = acc_a[r];
      float zv = acc_z[r];
      float zs = frcp(1.f + fexp2(-1.44269504f * zv));   // sigmoid(z)
      float u2 = fexp2(2.88539008f * av);
      float th = 1.f - 2.f * frcp(u2 + 1.f);             // tanh(a)
      float hn = th + zs * (hold[r] - th);
      hold[r] = hn;
      scr[scri + (rg * 4 + r) * 8] = (f16)hn;            // wave-local b16 scatter
    }
    // wave-local readback (lgkmcnt inserted by compiler; wave lockstep => no barrier)
    u32x2 pkt = *(const u32x2*)&scr[l * 4];
    {
      f16* dst = hx + (size_t)((t + 1) & 1) * 65536 + tileoff + pbase + (size_t)l * 4;
      asm volatile("global_store_dwordx2 %0, %1, off sc0 sc1" :: "v"(dst), "v"(pkt) : "memory");
    }
    asm volatile("s_waitcnt vmcnt(0)" ::: "memory");
    if (l == 0)
      __hip_atomic_store(&flags[sg * 32 + cg * 4 + w], (u32)(tagbase + t + 1),
                         __ATOMIC_RELAXED, __HIP_MEMORY_SCOPE_AGENT);

    // hs output from shuffled regs: one coalesced 8B store (off protocol path)
    *(u32x2*)&hs[((size_t)(s0 + srow2) * 500 + t) * 512 + col2] = pkt;

    // gate prefetch for t+1 (flies during next poll)
    int tn = (t + 1 < 500) ? t + 1 : 499;
    const f16* gb = gates + ((size_t)tn * 128 + s0 + rg * 4) * 1024;
#pragma unroll
    for (int r = 0; r < 4; ++r) { ga[r] = gb[r * 1024 + an0 + c]; gz[r] = gb[r * 1024 + zn0 + c]; }
  }
}

// ---------------- FC + pack ----------------
__global__ __launch_bounds__(256) void k_fc(const f16* __restrict__ hs,
                                            const f16* __restrict__ wfc,   // [72][1024] f16
                                            const float* __restrict__ bfc,
                                            const int* __restrict__ lens,
                                            const int* __restrict__ offs,
                                            float* __restrict__ out) {
  const int b = blockIdx.x, chunk = blockIdx.y;
  const int tid = threadIdx.x;
  __shared__ f16 X[16][1032];
#pragma unroll
  for (int ii = 0; ii < 8; ++ii) {
    int sg = ii * 256 + tid;
    int row = sg >> 7;
    int f = (sg & 127) * 8;
    int t = chunk * 16 + row;
    int tt = t < 500 ? t : 499;
    int half = f >> 9, col = f & 511;
    int seq = half ? 64 + b : b;
    int time = half ? 499 - tt : tt;
    *(half8*)&X[row][f] = *(const half8*)&hs[((size_t)seq * 500 + time) * 512 + col];
  }
  __syncthreads();
  int row = tid >> 4, og = tid & 15;
  int t = chunk * 16 + row;
  int len = lens[b];
  float acc[5];
#pragma unroll
  for (int j = 0; j < 5; ++j) {
    int o = j * 16 + og;
    acc[j] = (o < 72) ? bfc[o] : 0.f;
  }
  for (int k8 = 0; k8 < 128; ++k8) {
    half8 x8 = *(const half8*)&X[row][k8 * 8];
    float xf[8];
#pragma unroll
    for (int e = 0; e < 8; ++e) xf[e] = (float)x8[e];
#pragma unroll
    for (int j = 0; j < 5; ++j) {
      int o = j * 16 + og;
      int oc = o < 72 ? o : 0;
      half8 w8 = *(const half8*)&wfc[(size_t)oc * 1024 + k8 * 8];
#pragma unroll
      for (int e = 0; e < 8; ++e) acc[j] += xf[e] * (float)w8[e];
    }
  }
  if (t < 500 && t < len) {
    size_t base = ((size_t)offs[b] + t) * 72;
#pragma unroll
    for (int j = 0; j < 5; ++j) {
      int o = j * 16 + og;
      if (o < 72) out[base + o] = acc[j];
    }
  }
}

// ---------------- launcher ----------------

extern "C" void kernel_launch(void* const* d_in, const int* in_sizes, int n_in,
                              void* d_out, int out_size, void* d_ws, size_t ws_size,
                              hipStream_t stream) {
  const float* batch = (const float*)d_in[0];
  const int*   lens  = (const int*)d_in[1];
  const float* w0 = (const float*)d_in[2];
  const float* b0 = (const float*)d_in[3];
  const float* u0 = (const float*)d_in[4];
  const float* w1 = (const float*)d_in[5];
  const float* b1 = (const float*)d_in[6];
  const float* u1 = (const float*)d_in[7];
  const float* w2 = (const float*)d_in[8];
  const float* b2 = (const float*)d_in[9];
  const float* u2 = (const float*)d_in[10];
  const float* wfc = (const float*)d_in[11];
  const float* bfc = (const float*)d_in[12];
  float* out = (float*)d_out;

  char* ws = (char*)d_ws;
  const size_t GATES_OFF = 0;                  // [500][128][1024] f16 = 131,072,000
  const size_t HS_OFF    = 131072000;          // [128][500][512]  f16 =  65,536,000
  const size_t XB0_OFF   = 196608000;          // [128][500][96]   f16 =  12,288,000
  const size_t W0P_OFF   = 208896000;          // [1024][96]  f16
  const size_t W1_OFF    = 209092608;          // [1024][1024] f16
  const size_t W2_OFF    = 211189760;
  const size_t U0_OFF    = 213286912;          // [1024][512] f16
  const size_t U1_OFF    = 214335488;
  const size_t U2_OFF    = 215384064;
  const size_t WFC_OFF   = 216432640;          // [72][1024] f16
  const size_t OFFS_OFF  = 216580096;          // 64 ints
  const size_t HX_OFF    = 216581120;          // [2][8][8192] f16 = 262,144 B
  const size_t FLAGS_OFF = 216843264;          // [8][32] u32 = 1024 B

  f16* g_gates = (f16*)(ws + GATES_OFF);
  f16* g_hs    = (f16*)(ws + HS_OFF);
  f16* g_xb0   = (f16*)(ws + XB0_OFF);
  f16* g_w0p   = (f16*)(ws + W0P_OFF);
  f16* g_w1    = (f16*)(ws + W1_OFF);
  f16* g_w2    = (f16*)(ws + W2_OFF);
  f16* g_u0    = (f16*)(ws + U0_OFF);
  f16* g_u1    = (f16*)(ws + U1_OFF);
  f16* g_u2    = (f16*)(ws + U2_OFF);
  f16* g_wfc   = (f16*)(ws + WFC_OFF);
  int* g_offs  = (int*)(ws + OFFS_OFF);
  f16* g_hx    = (f16*)(ws + HX_OFF);
  u32* g_flags = (u32*)(ws + FLAGS_OFF);

  hipLaunchKernelGGL(k_offs, dim3(1), dim3(64), 0, stream, lens, g_offs);

  auto cvt = [&](const float* s, f16* d, int n) {
    hipLaunchKernelGGL(k_cvt, dim3((n + 255) / 256), dim3(256), 0, stream, s, d, n);
  };
  cvt(w1, g_w1, 1024 * 1024);
  cvt(w2, g_w2, 1024 * 1024);
  cvt(u0, g_u0, 1024 * 512);
  cvt(u1, g_u1, 1024 * 512);
  cvt(u2, g_u2, 1024 * 512);
  cvt(wfc, g_wfc, 72 * 1024);
  hipLaunchKernelGGL(k_w0pad, dim3((1024 * 96 + 255) / 256), dim3(256), 0, stream, w0, g_w0p);
  hipLaunchKernelGGL(k_xb0, dim3((128 * 500 * 96 + 255) / 256), dim3(256), 0, stream, batch, g_xb0);
  // zero flags (re-poisoned to 0xAA before every timed launch); monotone layer tags
  // make a single zeroing sufficient for all 3 k_rec launches. hx needs no init:
  // every word is written (and flagged) before any consumer reads it.
  hipLaunchKernelGGL(k_zero, dim3(1), dim3(256), 0, stream, g_flags, 256);

  // layer 0
  hipLaunchKernelGGL((k_gates<0>), dim3(500, 8), dim3(256), 0, stream, g_xb0, g_w0p, b0, g_gates);
  hipLaunchKernelGGL(k_rec, dim3(64), dim3(256), 0, stream, g_gates, g_u0, g_hs, g_hx, g_flags, 0);
  // layer 1
  hipLaunchKernelGGL((k_gates<1>), dim3(500, 8), dim3(256), 0, stream, g_hs, g_w1, b1, g_gates);
  hipLaunchKernelGGL(k_rec, dim3(64), dim3(256), 0, stream, g_gates, g_u1, g_hs, g_hx, g_flags, 512);
  // layer 2
  hipLaunchKernelGGL((k_gates<1>), dim3(500, 8), dim3(256), 0, stream, g_hs, g_w2, b2, g_gates);
  hipLaunchKernelGGL(k_rec, dim3(64), dim3(256), 0, stream, g_gates, g_u2, g_hs, g_hx, g_flags, 1024);

  // FC + pack
  hipLaunchKernelGGL(k_fc, dim3(64, 32), dim3(256), 0, stream, g_hs, g_wfc, bfc, lens, g_offs, out);
}